// Round 8
// baseline (233.229 us; speedup 1.0000x reference)
//
#include <hip/hip_runtime.h>

#define HH 299
#define WW 299
#define HW (HH * WW)
#define BORDER 3
#define NT 320

typedef float f4 __attribute__((ext_vector_type(4)));
typedef f4 __attribute__((aligned(4))) f4a;   // 4B-aligned float4 loads

__global__ __launch_bounds__(NT) void crop_resize_kernel(
    const float* __restrict__ x,   // (S, 3, H, W)
    const int*   __restrict__ f,   // (S, G, 4)
    float*       __restrict__ out, // (S, G, 3, H, W)
    int G, int total, int nblk)    // total = S*G*HH work items
{
    __shared__ float sV[2][3][304];   // double-buffered fused source row, 7.3 KB

    int b  = blockIdx.x;
    // XCD-contiguous: physical blocks with (b&7)==k take logical chunk k.
    // Consecutive items (same crop/image) stay on one XCD's L2.
    int lb = ((b & 7) * (nblk >> 3)) + (b >> 3);
    long long tl = (long long)total;
    int lo = (int)((tl * lb) / nblk);
    int hi = (int)((tl * (lb + 1)) / nblk);
    if (lo >= hi) return;

    int t    = threadIdx.x;
    int s_ch = t / 76;                 // staging: channel 0..2
    int s_q  = (t - s_ch * 76) << 2;   // staging: quad col offset 0,4,...,300
    bool stager = (t < 228);

    // ---- staging-side crop context ----
    int sg_st, tlx_st, tly_st, hc_st, wc_st;
    const float* img_st;

    int item = lo;
    int sg  = item / HH;
    int row = item - sg * HH;

    {   // load ctx for first crop
        const int* box = f + (sg << 2);
        tlx_st = max(box[0] - BORDER, 0);
        tly_st = max(box[1] - BORDER, 0);
        hc_st  = min(box[2] + BORDER, HH - 1) - tlx_st;
        wc_st  = min(box[3] + BORDER, WW - 1) - tly_st;
        img_st = x + (sg / G) * 3 * HW;
        sg_st  = sg;
    }

    // ---- prologue: stage item `lo` into buffer 0 ----
    int wc_cur = wc_st;
    {
        float hf = (float)hc_st;
        float sx = ((row + 0.5f) * hf) / (float)HH - 0.5f;
        sx = fminf(fmaxf(sx, 0.0f), hf - 1.0f);
        int bx = max(min((int)floorf(sx), hc_st - 2), 0);
        float fx = sx - (float)bx;
        float omfx = 1.0f - fx;
        if (stager && s_q < wc_st) {
            int c = min(s_q, wc_st - 3);     // clamped: 16B read stays in row
            const float* p = img_st + s_ch * HW + (tlx_st + bx) * WW + tly_st + c;
            f4 a  = *(const f4a*)p;          // source row bx
            f4 bb = *(const f4a*)(p + WW);   // source row bx+1
            sV[0][s_ch][c+0] = fmaf(a.x, omfx, bb.x * fx);
            sV[0][s_ch][c+1] = fmaf(a.y, omfx, bb.y * fx);
            sV[0][s_ch][c+2] = fmaf(a.z, omfx, bb.z * fx);
            sV[0][s_ch][c+3] = fmaf(a.w, omfx, bb.w * fx);
        }
    }
    __syncthreads();

    // ---- compute-side column-coord cache (valid per crop) ----
    int sg_col = -1;
    int by = 0; float fy = 0.0f, omfy = 0.0f;

    int cur = 0;
    int wc_nxt = wc_cur;

    for (; item < hi; ++item) {
        int row1 = row + 1, sg1 = sg;
        if (row1 == HH) { row1 = 0; sg1 = sg + 1; }
        bool have_next = (item + 1) < hi;

        // ---- (A) issue next item's staged loads (latency hides under B) ----
        f4 a, bb; float fx1 = 0.0f;
        bool do_st = false; int stc = 0;
        if (have_next) {
            if (sg1 != sg_st) {              // uniform branch, ~1 per 299 items
                const int* box = f + (sg1 << 2);
                tlx_st = max(box[0] - BORDER, 0);
                tly_st = max(box[1] - BORDER, 0);
                hc_st  = min(box[2] + BORDER, HH - 1) - tlx_st;
                wc_st  = min(box[3] + BORDER, WW - 1) - tly_st;
                img_st = x + (sg1 / G) * 3 * HW;
                sg_st  = sg1;
            }
            wc_nxt = wc_st;
            float hf = (float)hc_st;
            float sx = ((row1 + 0.5f) * hf) / (float)HH - 0.5f;
            sx = fminf(fmaxf(sx, 0.0f), hf - 1.0f);
            int bx = max(min((int)floorf(sx), hc_st - 2), 0);
            fx1 = sx - (float)bx;
            if (stager && s_q < wc_st) {
                do_st = true;
                stc = min(s_q, wc_st - 3);
                const float* p = img_st + s_ch * HW + (tlx_st + bx) * WW + tly_st + stc;
                a  = *(const f4a*)p;         // issued here, waited in (C)
                bb = *(const f4a*)(p + WW);
            }
        }

        // ---- (B) compute current item from sV[cur] ----
        if (sg != sg_col) {                  // uniform; wc_cur matches crop sg
            float wf = (float)wc_cur;
            float sy = ((t + 0.5f) * wf) / (float)WW - 0.5f;
            sy = fminf(fmaxf(sy, 0.0f), wf - 1.0f);
            by = max(min((int)floorf(sy), wc_cur - 2), 0);
            fy = sy - (float)by;
            omfy = 1.0f - fy;
            sg_col = sg;
        }
        if (t < WW) {
            int obase = (sg * 3 * HH + row) * WW + t;
            float v0 = fmaf(sV[cur][0][by], omfy, sV[cur][0][by+1] * fy);
            float v1 = fmaf(sV[cur][1][by], omfy, sV[cur][1][by+1] * fy);
            float v2 = fmaf(sV[cur][2][by], omfy, sV[cur][2][by+1] * fy);
            out[obase]          = v0;
            out[obase + HW]     = v1;
            out[obase + 2 * HW] = v2;
        }

        // ---- (C) finish stage: vmcnt wait + vertical fuse + LDS write ----
        if (do_st) {
            int nb = cur ^ 1;
            float omfx1 = 1.0f - fx1;
            sV[nb][s_ch][stc+0] = fmaf(a.x, omfx1, bb.x * fx1);
            sV[nb][s_ch][stc+1] = fmaf(a.y, omfx1, bb.y * fx1);
            sV[nb][s_ch][stc+2] = fmaf(a.z, omfx1, bb.z * fx1);
            sV[nb][s_ch][stc+3] = fmaf(a.w, omfx1, bb.w * fx1);
        }
        __syncthreads();
        cur ^= 1;
        sg = sg1; row = row1; wc_cur = wc_nxt;
    }
}

extern "C" void kernel_launch(void* const* d_in, const int* in_sizes, int n_in,
                              void* d_out, int out_size, void* d_ws, size_t ws_size,
                              hipStream_t stream) {
    const float* x = (const float*)d_in[0];
    const int*   f = (const int*)d_in[1];
    float* out = (float*)d_out;

    int S = in_sizes[0] / (3 * HW);   // 32
    int G = in_sizes[1] / (S * 4);    // 16
    int total = S * G * HH;           // 153088

    // Exactly-resident persistent grid: blocks/CU from the runtime (accounts
    // for VGPR/LDS/wave limits), x 256 CUs. Host-side query, capture-safe.
    int occ = 0;
    (void)hipOccupancyMaxActiveBlocksPerMultiprocessor(
        &occ, (const void*)crop_resize_kernel, NT, 0);
    if (occ < 1) occ = 1;
    int nblk = occ * 256;             // divisible by 8 for the XCD split
    if (nblk > total) nblk = (total / 8) * 8;

    dim3 grid((unsigned)nblk);
    dim3 block(NT);
    crop_resize_kernel<<<grid, block, 0, stream>>>(x, f, out, G, total, nblk);
}

// Round 9
// 170.557 us; speedup vs baseline: 1.3675x; 1.3675x over previous
//
#include <hip/hip_runtime.h>

#define HH 299
#define WW 299
#define HW (HH * WW)
#define BORDER 3
#define NT 320
#define RPB 2
#define PAIRS 150            // ceil(299/2)
#define INV299 (1.0f / 299.0f)

typedef float f4 __attribute__((ext_vector_type(4)));
typedef f4 __attribute__((aligned(4))) f4a;   // 4B-aligned float4 loads

__global__ __launch_bounds__(NT) void crop_resize_kernel(
    const float* __restrict__ x,   // (S, 3, H, W)
    const int*   __restrict__ f,   // (S, G, 4)
    float*       __restrict__ out, // (S, G, 3, H, W)
    int G)
{
    __shared__ float sV[RPB][3][304];   // fused vertical rows, 7.3 KB

    // Bijective XCD swizzle (grid = 76800 = 8 * 9600): contiguous logical
    // chunks per XCD -> a crop's blocks (and its image) stay in one L2.
    int cpx = (int)(gridDim.x >> 3);
    int hb  = blockIdx.x;
    int blk = (hb & 7) * cpx + (hb >> 3);

    int sg = blk / PAIRS;               // crop index si*G + gi
    int r0 = (blk - sg * PAIRS) * RPB;  // first output row of this block
    int si = sg / G;

    const int* box = f + (sg << 2);
    int tlx = max(box[0] - BORDER, 0);
    int tly = max(box[1] - BORDER, 0);
    int hc  = min(box[2] + BORDER, HH - 1) - tlx;
    int wc  = min(box[3] + BORDER, WW - 1) - tly;

    int t = threadIdx.x;
    const float* img = x + si * 3 * HW;

    // Row (x-axis) coords for both rows — block-uniform, division-free.
    float hstep = (float)hc * INV299;
    int   gxb[RPB]; float fxa[RPB];
    #pragma unroll
    for (int r = 0; r < RPB; ++r) {
        int row = min(r0 + r, HH - 1);           // tail dup is harmless
        float sx = fmaf((float)row + 0.5f, hstep, -0.5f);
        sx = fminf(fmaxf(sx, 0.0f), (float)hc - 1.0f);
        int bx = max(min((int)floorf(sx), hc - 2), 0);
        fxa[r] = sx - (float)bx;
        gxb[r] = tlx + bx;
    }

    // Staging: unit u in [0, 456): r = u/228, ch = (u%228)/76, quad q.
    // Two units per thread (t < 136 gets the second); all loads independent.
    #pragma unroll
    for (int pass = 0; pass < 2; ++pass) {
        int u = t + pass * NT;
        if (u < RPB * 228) {
            int r  = u / 228;
            int m  = u - r * 228;
            int ch = m / 76;
            int q  = (m - ch * 76) << 2;
            if (q < wc) {
                int c = min(q, wc - 3);          // 16B read stays inside row
                const float* p = img + ch * HW + gxb[r] * WW + tly + c;
                f4 a = *(const f4a*)p;           // source row bx
                f4 b = *(const f4a*)(p + WW);    // source row bx+1
                float fr = fxa[r], om = 1.0f - fr;
                sV[r][ch][c + 0] = fmaf(a.x, om, b.x * fr);
                sV[r][ch][c + 1] = fmaf(a.y, om, b.y * fr);
                sV[r][ch][c + 2] = fmaf(a.z, om, b.z * fr);
                sV[r][ch][c + 3] = fmaf(a.w, om, b.w * fr);
            }
        }
    }
    __syncthreads();

    if (t >= WW) return;   // 299 active lanes, single pass

    // Column (y-axis) coords — per thread, ONCE for both rows (same crop).
    float sy = fmaf((float)t + 0.5f, (float)wc * INV299, -0.5f);
    sy = fminf(fmaxf(sy, 0.0f), (float)wc - 1.0f);
    int by = max(min((int)floorf(sy), wc - 2), 0);
    float fy   = sy - (float)by;
    float omfy = 1.0f - fy;

    #pragma unroll
    for (int r = 0; r < RPB; ++r) {
        int row = r0 + r;
        if (row < HH) {                          // uniform guard (tail block)
            int obase = (sg * 3 * HH + row) * WW + t;
            #pragma unroll
            for (int ch = 0; ch < 3; ++ch) {
                out[obase + ch * HW] =
                    fmaf(sV[r][ch][by], omfy, sV[r][ch][by + 1] * fy);
            }
        }
    }
}

extern "C" void kernel_launch(void* const* d_in, const int* in_sizes, int n_in,
                              void* d_out, int out_size, void* d_ws, size_t ws_size,
                              hipStream_t stream) {
    const float* x = (const float*)d_in[0];
    const int*   f = (const int*)d_in[1];
    float* out = (float*)d_out;

    int S = in_sizes[0] / (3 * HW);   // 32
    int G = in_sizes[1] / (S * 4);    // 16

    dim3 grid((unsigned)(S * G * PAIRS));  // 76800 = 8 * 9600
    dim3 block(NT);
    crop_resize_kernel<<<grid, block, 0, stream>>>(x, f, out, G);
}

// Round 10
// 153.823 us; speedup vs baseline: 1.5162x; 1.1088x over previous
//
#include <hip/hip_runtime.h>

#define HH 299
#define WW 299
#define HW (HH * WW)
#define BORDER 3
#define NT 320
#define RPB 4
#define CHUNKS 75            // ceil(299/4)
#define INV299 (1.0f / 299.0f)

typedef float f4 __attribute__((ext_vector_type(4)));
typedef f4 __attribute__((aligned(4))) f4a;   // 4B-aligned float4 loads

__global__ __launch_bounds__(NT) void crop_resize_kernel(
    const float* __restrict__ x,   // (S, 3, H, W)
    const int*   __restrict__ f,   // (S, G, 4)
    float*       __restrict__ out, // (S, G, 3, H, W)
    int G)
{
    __shared__ float sV[RPB][3][304];   // fused vertical rows, 14.6 KB

    // Bijective XCD swizzle (grid = 38400 = 8 * 4800): contiguous logical
    // chunks per XCD -> a crop's blocks (and its image) stay in one L2.
    int cpx = (int)(gridDim.x >> 3);
    int hb  = blockIdx.x;
    int blk = (hb & 7) * cpx + (hb >> 3);

    int sg = blk / CHUNKS;               // crop index si*G + gi
    int r0 = (blk - sg * CHUNKS) * RPB;  // first output row of this block
    int si = sg / G;

    const int* box = f + (sg << 2);
    int tlx = max(box[0] - BORDER, 0);
    int tly = max(box[1] - BORDER, 0);
    int hc  = min(box[2] + BORDER, HH - 1) - tlx;
    int wc  = min(box[3] + BORDER, WW - 1) - tly;

    int t = threadIdx.x;
    const float* img = x + si * 3 * HW;

    // Row (x-axis) coords for RPB rows — block-uniform, division-free.
    float hstep = (float)hc * INV299;
    int   gxb[RPB]; float fxa[RPB];
    #pragma unroll
    for (int r = 0; r < RPB; ++r) {
        int row = min(r0 + r, HH - 1);           // tail dup is harmless
        float sx = fmaf((float)row + 0.5f, hstep, -0.5f);
        sx = fminf(fmaxf(sx, 0.0f), (float)hc - 1.0f);
        int bx = max(min((int)floorf(sx), hc - 2), 0);
        fxa[r] = sx - (float)bx;
        gxb[r] = tlx + bx;
    }

    // Staging: unit u in [0, RPB*228): r = u/228, ch = (u%228)/76, quad q.
    // 912 units over 320 threads -> 3 passes, all loads independent.
    #pragma unroll
    for (int pass = 0; pass < 3; ++pass) {
        int u = t + pass * NT;
        if (u < RPB * 228) {
            int r  = u / 228;
            int m  = u - r * 228;
            int ch = m / 76;
            int q  = (m - ch * 76) << 2;
            if (q < wc) {
                int c = min(q, wc - 3);          // 16B read stays inside row
                const float* p = img + ch * HW + gxb[r] * WW + tly + c;
                f4 a = *(const f4a*)p;           // source row bx
                f4 b = *(const f4a*)(p + WW);    // source row bx+1
                float fr = fxa[r], om = 1.0f - fr;
                sV[r][ch][c + 0] = fmaf(a.x, om, b.x * fr);
                sV[r][ch][c + 1] = fmaf(a.y, om, b.y * fr);
                sV[r][ch][c + 2] = fmaf(a.z, om, b.z * fr);
                sV[r][ch][c + 3] = fmaf(a.w, om, b.w * fr);
            }
        }
    }
    __syncthreads();

    if (t >= WW) return;   // 299 active lanes, single pass

    // Column (y-axis) coords — per thread, ONCE for all RPB rows (same crop).
    float sy = fmaf((float)t + 0.5f, (float)wc * INV299, -0.5f);
    sy = fminf(fmaxf(sy, 0.0f), (float)wc - 1.0f);
    int by = max(min((int)floorf(sy), wc - 2), 0);
    float fy   = sy - (float)by;
    float omfy = 1.0f - fy;

    #pragma unroll
    for (int r = 0; r < RPB; ++r) {
        int row = r0 + r;
        if (row < HH) {                          // uniform guard (tail block)
            int obase = (sg * 3 * HH + row) * WW + t;
            #pragma unroll
            for (int ch = 0; ch < 3; ++ch) {
                out[obase + ch * HW] =
                    fmaf(sV[r][ch][by], omfy, sV[r][ch][by + 1] * fy);
            }
        }
    }
}

extern "C" void kernel_launch(void* const* d_in, const int* in_sizes, int n_in,
                              void* d_out, int out_size, void* d_ws, size_t ws_size,
                              hipStream_t stream) {
    const float* x = (const float*)d_in[0];
    const int*   f = (const int*)d_in[1];
    float* out = (float*)d_out;

    int S = in_sizes[0] / (3 * HW);   // 32
    int G = in_sizes[1] / (S * 4);    // 16

    dim3 grid((unsigned)(S * G * CHUNKS));  // 38400 = 8 * 4800
    dim3 block(NT);
    crop_resize_kernel<<<grid, block, 0, stream>>>(x, f, out, G);
}